// Round 15
// baseline (145.365 us; speedup 1.0000x reference)
//
#include <hip/hip_runtime.h>
#include <cstdint>
#include <cstddef>

#define D_MODEL 1024
#define HD 64
#define NH 16
#define SEQ 2048
#define NB 2

typedef __attribute__((ext_vector_type(8))) short bf8;           // 8 bf16 (4 VGPR)
typedef __attribute__((ext_vector_type(8))) unsigned short us8;
typedef __attribute__((ext_vector_type(4))) unsigned short us4;
typedef __attribute__((ext_vector_type(4))) float f4;

__device__ __forceinline__ float bf2f(unsigned short u) {
  union { unsigned int i; float f; } c; c.i = ((unsigned int)u) << 16; return c.f;
}
__device__ __forceinline__ unsigned short f2bf(float x) {
  union { float f; unsigned int i; } c; c.f = x;
  unsigned int r = (c.i + 0x7FFFu + ((c.i >> 16) & 1u)) >> 16;   // RNE
  return (unsigned short)r;
}
// packed f32x2 -> bf16x2 (RNE), single HW op
__device__ __forceinline__ unsigned int pkbf(float lo, float hi) {
  unsigned int r;
  asm("v_cvt_pk_bf16_f32 %0, %1, %2" : "=v"(r) : "v"(lo), "v"(hi));
  return r;
}
// exp2 via v_exp_f32 (D = 2^S0)
__device__ __forceinline__ float ex2(float x) {
  float r;
  asm("v_exp_f32 %0, %1" : "=v"(r) : "v"(x));
  return r;
}
__device__ __forceinline__ f4 mfma16(bf8 a, bf8 b, f4 c) {
  return __builtin_amdgcn_mfma_f32_16x16x32_bf16(a, b, c, 0, 0, 0);
}
// async global->LDS, 16B per lane; LDS dest = wave-uniform base + lane*16
__device__ __forceinline__ void gl16(const unsigned short* g, unsigned short* l) {
  __builtin_amdgcn_global_load_lds(
      (const __attribute__((address_space(1))) unsigned int*)g,
      (__attribute__((address_space(3))) unsigned int*)l, 16, 0, 0);
}

#define QSCALE (0.125f * 1.44269504088896f)   // 1/sqrt(64) * log2(e)

// ---------------- prep: weight transpose -> W^T hi (bf16), all 4 mats ----------------
__global__ __launch_bounds__(256) void prep_weights(
    const float* __restrict__ Wq, const float* __restrict__ Wk,
    const float* __restrict__ Wv, const float* __restrict__ Wo,
    unsigned short* __restrict__ wthi) {
  int bid = blockIdx.x;
  int mat = bid >> 10, rem = bid & 1023;
  int kt = (rem >> 5) * 32, nt = (rem & 31) * 32;
  const float* W = (mat == 0) ? Wq : (mat == 1) ? Wk : (mat == 2) ? Wv : Wo;
  unsigned short* oh = wthi + ((size_t)mat << 20);
  __shared__ float ls[32][33];
  int i = threadIdx.x >> 5;
  int jj = threadIdx.x & 31;
#pragma unroll
  for (int ii = 0; ii < 4; ++ii) {
    int r = i + ii * 8;
    ls[r][jj] = W[(size_t)(kt + r) * D_MODEL + nt + jj];
  }
  __syncthreads();
#pragma unroll
  for (int ii = 0; ii < 4; ++ii) {
    int r = i + ii * 8;
    float v = ls[jj][r];
    if (mat == 0) v *= QSCALE;
    oh[(size_t)(nt + r) * D_MODEL + kt + jj] = f2bf(v);
  }
}

// ---------------- proj GEMM: fp32 A with inline bf16 convert, hi-only B ----------------
__global__ __launch_bounds__(256, 3) void proj_gemm(
    const float* __restrict__ Qin, const float* __restrict__ Kin,
    const float* __restrict__ Vin, const unsigned short* __restrict__ wth,
    const float* __restrict__ b0, const float* __restrict__ b1,
    const float* __restrict__ b2,
    unsigned short* __restrict__ qh, unsigned short* __restrict__ kh,
    unsigned short* __restrict__ vt) {
  // 768 = 8 XCDs x 96: wid chunked per XCD; bn fastest within chunk
  int wid = (blockIdx.x & 7) * 96 + (blockIdx.x >> 3);
  int z = wid >> 8, rem = wid & 255, bm = rem >> 3, bn = rem & 7;

  const float* A = (z == 0) ? Qin : (z == 1) ? Kin : Vin;
  const unsigned short* Bh = wth + ((size_t)z << 20);
  const float* bias = (z == 0) ? b0 : (z == 1) ? b1 : b2;
  float bsc = (z == 0) ? QSCALE : 1.0f;

  int tid = threadIdx.x, lane = tid & 63, w = tid >> 6;
  int wr = w >> 1, wc = w & 1, l16 = lane & 15, l4 = lane >> 4;

  __shared__ unsigned short As[2][128 * 32];
  __shared__ unsigned short Bsh[2][128 * 32];

  const float* Ab = A + (size_t)(bm * 128) * D_MODEL;
  const unsigned short* Bhb = Bh + (size_t)(bn * 128) * D_MODEL;

  int r0 = tid >> 2, g0 = tid & 3;
  int r1 = (256 + tid) >> 2, g1 = tid & 3;
  int s0 = (r0 ^ (r0 >> 2)) & 3, s1 = (r1 ^ (r1 >> 2)) & 3;
  size_t so0 = (size_t)r0 * D_MODEL + ((g0 ^ s0) * 8);
  size_t so1 = (size_t)r1 * D_MODEL + ((g1 ^ s1) * 8);
  int ld0 = (w * 64) * 8;
  int ld1 = (256 + w * 64) * 8;

  int rr = tid >> 2, c8 = (tid & 3) * 8;
  int adst[2];
#pragma unroll
  for (int p = 0; p < 2; ++p) {
    int row = p * 64 + rr;
    int sw = (row ^ (row >> 2)) & 3;
    adst[p] = row * 32 + (((tid & 3) ^ sw)) * 8;
  }

  int offA[4], offB[4];
#pragma unroll
  for (int m = 0; m < 4; ++m) {
    int row = wr * 64 + m * 16 + l16;
    int sw = (row ^ (row >> 2)) & 3;
    offA[m] = row * 32 + ((l4 ^ sw)) * 8;
  }
#pragma unroll
  for (int n = 0; n < 4; ++n) {
    int row = wc * 64 + n * 16 + l16;
    int sw = (row ^ (row >> 2)) & 3;
    offB[n] = row * 32 + ((l4 ^ sw)) * 8;
  }

  f4 acc[4][4];
  const f4 zf = {0.f, 0.f, 0.f, 0.f};
#pragma unroll
  for (int m = 0; m < 4; ++m)
#pragma unroll
    for (int n = 0; n < 4; ++n) acc[m][n] = zf;

  {
    float4 x[2][2];
#pragma unroll
    for (int p = 0; p < 2; ++p) {
      const float* src = Ab + (size_t)(p * 64 + rr) * D_MODEL + c8;
      x[p][0] = *reinterpret_cast<const float4*>(src);
      x[p][1] = *reinterpret_cast<const float4*>(src + 4);
    }
    gl16(Bhb + so0, &Bsh[0][ld0]);
    gl16(Bhb + so1, &Bsh[0][ld1]);
#pragma unroll
    for (int p = 0; p < 2; ++p) {
      union { us8 v; unsigned u[4]; } hv;
      hv.u[0] = pkbf(x[p][0].x, x[p][0].y); hv.u[1] = pkbf(x[p][0].z, x[p][0].w);
      hv.u[2] = pkbf(x[p][1].x, x[p][1].y); hv.u[3] = pkbf(x[p][1].z, x[p][1].w);
      *reinterpret_cast<us8*>(&As[0][adst[p]]) = hv.v;
    }
  }
  __syncthreads();

  int cur = 0;
  for (int i = 0; i < 32; ++i) {
    float4 nx[2][2];
    if (i < 31) {
      int ktn = (i + 1) * 32;
#pragma unroll
      for (int p = 0; p < 2; ++p) {
        const float* src = Ab + (size_t)(p * 64 + rr) * D_MODEL + ktn + c8;
        nx[p][0] = *reinterpret_cast<const float4*>(src);
        nx[p][1] = *reinterpret_cast<const float4*>(src + 4);
      }
      gl16(Bhb + ktn + so0, &Bsh[cur ^ 1][ld0]);
      gl16(Bhb + ktn + so1, &Bsh[cur ^ 1][ld1]);
    }
    bf8 a[4], bh[4];
#pragma unroll
    for (int m = 0; m < 4; ++m)
      a[m] = *reinterpret_cast<const bf8*>(&As[cur][offA[m]]);
#pragma unroll
    for (int n = 0; n < 4; ++n)
      bh[n] = *reinterpret_cast<const bf8*>(&Bsh[cur][offB[n]]);
#pragma unroll
    for (int m = 0; m < 4; ++m)
#pragma unroll
      for (int n = 0; n < 4; ++n)
        acc[m][n] = mfma16(a[m], bh[n], acc[m][n]);
    if (i < 31) {
#pragma unroll
      for (int p = 0; p < 2; ++p) {
        union { us8 v; unsigned u[4]; } hv;
        hv.u[0] = pkbf(nx[p][0].x, nx[p][0].y); hv.u[1] = pkbf(nx[p][0].z, nx[p][0].w);
        hv.u[2] = pkbf(nx[p][1].x, nx[p][1].y); hv.u[3] = pkbf(nx[p][1].z, nx[p][1].w);
        *reinterpret_cast<us8*>(&As[cur ^ 1][adst[p]]) = hv.v;
      }
    }
    __syncthreads();
    cur ^= 1;
  }

#pragma unroll
  for (int n = 0; n < 4; ++n) {
    int col = bn * 128 + wc * 64 + n * 16 + l16;
    float bb = bias[col] * bsc;
#pragma unroll
    for (int m = 0; m < 4; ++m) {
      int row0 = bm * 128 + wr * 64 + m * 16 + l4 * 4;
      if (z == 0) {
#pragma unroll
        for (int r = 0; r < 4; ++r)
          qh[(size_t)(row0 + r) * D_MODEL + col] = f2bf(acc[m][n][r] + bb);
      } else if (z == 1) {
#pragma unroll
        for (int r = 0; r < 4; ++r)
          kh[(size_t)(row0 + r) * D_MODEL + col] = f2bf(acc[m][n][r] + bb);
      } else {
        int bb2 = row0 >> 11, ss = row0 & (SEQ - 1);
        int hh2 = col >> 6, dd = col & 63;
        union { us4 s; uint2 u; } pk4;
        pk4.u.x = pkbf(acc[m][n][0] + bb, acc[m][n][1] + bb);
        pk4.u.y = pkbf(acc[m][n][2] + bb, acc[m][n][3] + bb);
        *reinterpret_cast<us4*>(vt + ((size_t)(bb2 * NH + hh2) * HD + dd) * SEQ + ss) = pk4.s;
      }
    }
  }
}

// ---------------- out GEMM (hi-only, fp32 out): 128x64 tile, 512 blocks, XCD swizzle ----------------
__global__ __launch_bounds__(256, 3) void out_gemm(
    const unsigned short* __restrict__ ah, const unsigned short* __restrict__ wth,
    const float* __restrict__ bo, float* __restrict__ o32) {
  int wid = (blockIdx.x & 7) * 64 + (blockIdx.x >> 3);
  int bm = wid >> 4, bn = wid & 15;

  const unsigned short* Bh = wth + ((size_t)3 << 20);
  int tid = threadIdx.x, lane = tid & 63, w = tid >> 6;
  int wr = w >> 1, wc = w & 1, l16 = lane & 15, l4 = lane >> 4;

  __shared__ unsigned short As[2][128 * 32];
  __shared__ unsigned short Bsh[2][64 * 32];

  const unsigned short* Ab = ah + (size_t)(bm * 128) * D_MODEL;
  const unsigned short* Bhb = Bh + (size_t)(bn * 64) * D_MODEL;

  int r0 = tid >> 2, g0 = tid & 3;
  int r1 = (256 + tid) >> 2;
  int s0 = (r0 ^ (r0 >> 2)) & 3, s1 = (r1 ^ (r1 >> 2)) & 3;
  size_t so0 = (size_t)r0 * D_MODEL + ((g0 ^ s0) * 8);
  size_t so1 = (size_t)r1 * D_MODEL + ((g0 ^ s1) * 8);
  int ld0 = (w * 64) * 8;
  int ld1 = (256 + w * 64) * 8;

  int offA[4], offB[2];
#pragma unroll
  for (int m = 0; m < 4; ++m) {
    int row = wr * 64 + m * 16 + l16;
    int sw = (row ^ (row >> 2)) & 3;
    offA[m] = row * 32 + ((l4 ^ sw)) * 8;
  }
#pragma unroll
  for (int n = 0; n < 2; ++n) {
    int row = wc * 32 + n * 16 + l16;
    int sw = (row ^ (row >> 2)) & 3;
    offB[n] = row * 32 + ((l4 ^ sw)) * 8;
  }

  f4 acc[4][2];
  const f4 zf = {0.f, 0.f, 0.f, 0.f};
#pragma unroll
  for (int m = 0; m < 4; ++m)
#pragma unroll
    for (int n = 0; n < 2; ++n) acc[m][n] = zf;

  gl16(Ab + so0, &As[0][ld0]); gl16(Ab + so1, &As[0][ld1]);
  gl16(Bhb + so0, &Bsh[0][ld0]);
  __syncthreads();

  int cur = 0;
  for (int i = 0; i < 32; ++i) {
    if (i < 31) {
      int ktn = (i + 1) * 32;
      gl16(Ab + ktn + so0, &As[cur ^ 1][ld0]); gl16(Ab + ktn + so1, &As[cur ^ 1][ld1]);
      gl16(Bhb + ktn + so0, &Bsh[cur ^ 1][ld0]);
    }
    bf8 a[4], bh[2];
#pragma unroll
    for (int m = 0; m < 4; ++m)
      a[m] = *reinterpret_cast<const bf8*>(&As[cur][offA[m]]);
#pragma unroll
    for (int n = 0; n < 2; ++n)
      bh[n] = *reinterpret_cast<const bf8*>(&Bsh[cur][offB[n]]);
#pragma unroll
    for (int m = 0; m < 4; ++m)
#pragma unroll
      for (int n = 0; n < 2; ++n)
        acc[m][n] = mfma16(a[m], bh[n], acc[m][n]);
    __syncthreads();
    cur ^= 1;
  }

#pragma unroll
  for (int n = 0; n < 2; ++n) {
    int col = bn * 64 + wc * 32 + n * 16 + l16;
    float bb = bo[col];
#pragma unroll
    for (int m = 0; m < 4; ++m) {
      int row0 = bm * 128 + wr * 64 + m * 16 + l4 * 4;
#pragma unroll
      for (int r = 0; r < 4; ++r)
        o32[(size_t)(row0 + r) * D_MODEL + col] = acc[m][n][r] + bb;
    }
  }
}

// ---------------- flash attention: 64 q/wave (256 q/block), KVBLK=128, paired-window PV ----------------
// 256 blocks (1/CU, 4 waves = 1 wave/SIMD). Each wave owns 64 q-rows (m=0..3),
// halving the per-CU LDS-unit traffic for K/V fragment reads (the r14-identified
// bottleneck: all waves read identical K/V frags; amortize over 2x q).
// Latency hiding via ILP (4 independent m streams, processed in 2 mg pairs).
__global__ __launch_bounds__(256, 1) void attn_kernel(
    const unsigned short* __restrict__ qh, const unsigned short* __restrict__ kh,
    const unsigned short* __restrict__ vt, unsigned short* __restrict__ aout) {
  // XCD-aware bijective swizzle: 256 blocks, 8 XCDs -> 32 contiguous per XCD
  int orig = blockIdx.x + (blockIdx.y << 3) + (blockIdx.z << 7);
  int swz = ((orig & 7) << 5) + (orig >> 3);
  int qt = swz & 7, h = (swz >> 3) & 15, b = swz >> 7;

  int tid = threadIdx.x;
  int lane = tid & 63, w = tid >> 6;
  int l16 = lane & 15, l4 = lane >> 4;
  int l8r = lane >> 3, l8c = lane & 7;

  __shared__ unsigned short lds[32768];   // [2][8192] K + [2][8192] V^T (64KB)

  const unsigned short* Kh = kh + (size_t)b * SEQ * D_MODEL + h * HD;
  const unsigned short* Vt = vt + (size_t)(b * NH + h) * HD * SEQ;

  // q B-frags: rows qt*256 + w*64 + m*16 + l16
  bf8 qf[4][2];
#pragma unroll
  for (int m = 0; m < 4; ++m) {
    size_t qo = (size_t)(b * SEQ + qt * 256 + w * 64 + m * 16 + l16) * D_MODEL + h * HD + l4 * 8;
    qf[m][0] = *reinterpret_cast<const bf8*>(qh + qo);
    qf[m][1] = *reinterpret_cast<const bf8*>(qh + qo + 32);
  }
  bf8 ones;
#pragma unroll
  for (int j = 0; j < 8; ++j) ones[j] = (short)0x3F80;

  const f4 zf = {0.f, 0.f, 0.f, 0.f};
  f4 acc[4][4];
  f4 accs[4] = {zf, zf, zf, zf};
  float mr[4] = {0.f, 0.f, 0.f, 0.f};
#pragma unroll
  for (int m = 0; m < 4; ++m)
#pragma unroll
    for (int nt = 0; nt < 4; ++nt) acc[m][nt] = zf;

  const int sgr = (l8c ^ l8r) * 8;     // K-staging pre-swizzled source granule
  const int swk = l16 & 7;
  const int vsub = ((l4 & 1) << 2);
  const int vrow_in = lane >> 4;       // 0..3 within V staging chunk

  // ---- stage tile 0 (128 keys) into buf 0 ----
  {
#pragma unroll
    for (int j = 0; j < 4; ++j) {
      int s = w * 4 + j;
      gl16(Kh + (size_t)(8 * s + l8r) * D_MODEL + sgr, &lds[0 + s * 512]);
      int row = 4 * s + vrow_in;
      int g = ((lane & 7) ^ (row & 7)) | (lane & 8);
      gl16(Vt + (size_t)row * SEQ + g * 8, &lds[16384 + s * 512]);
    }
  }
  __syncthreads();

  int cur = 0;
  for (int kt = 0; kt < SEQ / 128; ++kt) {
    if (kt < SEQ / 128 - 1) {
      int k0n = (kt + 1) * 128;
      unsigned short* kd = &lds[(cur ^ 1) * 8192];
      unsigned short* vd = &lds[16384 + (cur ^ 1) * 8192];
#pragma unroll
      for (int j = 0; j < 4; ++j) {
        int s = w * 4 + j;
        gl16(Kh + (size_t)(k0n + 8 * s + l8r) * D_MODEL + sgr, kd + s * 512);
        int row = 4 * s + vrow_in;
        int g = ((lane & 7) ^ (row & 7)) | (lane & 8);
        gl16(Vt + (size_t)row * SEQ + k0n + g * 8, vd + s * 512);
      }
    }
    const unsigned short* khb = &lds[cur * 8192];
    const unsigned short* vlb = &lds[16384 + cur * 8192];

#pragma unroll
    for (int h2 = 0; h2 < 2; ++h2) {
      const unsigned short* khh = khb + h2 * 4096;   // rows h2*64.. of [128][64]
      // K A-frags (shared by all m): A[row=key(half-local), k=d]
      bf8 kb[4][2];
#pragma unroll
      for (int c = 0; c < 4; ++c) {
        int row = c * 16 + l16;
        kb[c][0] = *reinterpret_cast<const bf8*>(&khh[row * 64 + ((l4 ^ swk) * 8)]);
        kb[c][1] = *reinterpret_cast<const bf8*>(&khh[row * 64 + (((4 + l4) ^ swk) * 8)]);
      }
      // V chunks (shared by all m)
      uint2 vdr[4][4];
#pragma unroll
      for (int c = 0; c < 4; ++c) {
        int gvc = 2 * c + (l4 >> 1);
        int voff = (((gvc ^ swk) + 8 * h2) << 3) + vsub;
#pragma unroll
        for (int nt = 0; nt < 4; ++nt)
          vdr[c][nt] = *reinterpret_cast<const uint2*>(&vlb[(nt * 16 + l16) * 128 + voff]);
      }
      // process 4 m's in 2 pairs (bounds live registers for sc/Wp)
#pragma unroll
      for (int mg = 0; mg < 2; ++mg) {
        f4 sc[2][4];
        __builtin_amdgcn_s_setprio(1);
#pragma unroll
        for (int mi = 0; mi < 2; ++mi)
#pragma unroll
          for (int c = 0; c < 4; ++c) {
            f4 sv = zf;
            sv = mfma16(kb[c][0], qf[mg * 2 + mi][0], sv);
            sv = mfma16(kb[c][1], qf[mg * 2 + mi][1], sv);
            sc[mi][c] = sv;
          }
        __builtin_amdgcn_s_setprio(0);
        unsigned Wp[2][4][2];
#pragma unroll
        for (int mi = 0; mi < 2; ++mi) {
          int m = mg * 2 + mi;
          float tc0 = fmaxf(fmaxf(sc[mi][0][0], sc[mi][0][1]), fmaxf(sc[mi][0][2], sc[mi][0][3]));
          float tc1 = fmaxf(fmaxf(sc[mi][1][0], sc[mi][1][1]), fmaxf(sc[mi][1][2], sc[mi][1][3]));
          float tc2 = fmaxf(fmaxf(sc[mi][2][0], sc[mi][2][1]), fmaxf(sc[mi][2][2], sc[mi][2][3]));
          float tc3 = fmaxf(fmaxf(sc[mi][3][0], sc[mi][3][1]), fmaxf(sc[mi][3][2], sc[mi][3][3]));
          float tm = fmaxf(fmaxf(tc0, tc1), fmaxf(tc2, tc3));
          tm = fmaxf(tm, __shfl_xor(tm, 16));
          tm = fmaxf(tm, __shfl_xor(tm, 32));
          if (__any(tm > mr[m] + 8.0f)) {
            float mn = fmaxf(mr[m], tm);
            float al = ex2(mr[m] - mn);
            mr[m] = mn;
            accs[m][0] *= al; accs[m][1] *= al; accs[m][2] *= al; accs[m][3] *= al;
#pragma unroll
            for (int nt = 0; nt < 4; ++nt) {
              acc[m][nt][0] *= al; acc[m][nt][1] *= al;
              acc[m][nt][2] *= al; acc[m][nt][3] *= al;
            }
          }
#pragma unroll
          for (int c = 0; c < 4; ++c) {
            float p0 = ex2(sc[mi][c][0] - mr[m]);
            float p1 = ex2(sc[mi][c][1] - mr[m]);
            float p2 = ex2(sc[mi][c][2] - mr[m]);
            float p3 = ex2(sc[mi][c][3] - mr[m]);
            Wp[mi][c][0] = pkbf(p0, p1);
            Wp[mi][c][1] = pkbf(p2, p3);
          }
        }
        // PV + denominator: two 16-key windows packed per K=32 MFMA
        __builtin_amdgcn_s_setprio(1);
#pragma unroll
        for (int cp = 0; cp < 2; ++cp) {
          int c0 = cp * 2, c1 = cp * 2 + 1;
#pragma unroll
          for (int mi = 0; mi < 2; ++mi) {
            int m = mg * 2 + mi;
            union { bf8 v; unsigned u[4]; } pu;
            pu.u[0] = Wp[mi][c0][0]; pu.u[1] = Wp[mi][c0][1];
            pu.u[2] = Wp[mi][c1][0]; pu.u[3] = Wp[mi][c1][1];
            accs[m] = mfma16(ones, pu.v, accs[m]);
#pragma unroll
            for (int nt = 0; nt < 4; ++nt) {
              union { bf8 v; unsigned u[4]; } vu;
              vu.u[0] = vdr[c0][nt].x; vu.u[1] = vdr[c0][nt].y;
              vu.u[2] = vdr[c1][nt].x; vu.u[3] = vdr[c1][nt].y;
              acc[m][nt] = mfma16(vu.v, pu.v, acc[m][nt]);
            }
          }
        }
        __builtin_amdgcn_s_setprio(0);
      }
    }
    __syncthreads();
    cur ^= 1;
  }

  // epilogue: normalize, transpose O^T -> O via freed LDS (256 q x 64 d = 32KB)
  float inv[4];
#pragma unroll
  for (int m = 0; m < 4; ++m) inv[m] = 1.0f / accs[m][0];
#pragma unroll
  for (int m = 0; m < 4; ++m) {
    int q = w * 64 + m * 16 + l16;
    int sw = (q & 7) << 3;
#pragma unroll
    for (int nt = 0; nt < 4; ++nt) {
      uint2 pw;
      pw.x = pkbf(acc[m][nt][0] * inv[m], acc[m][nt][1] * inv[m]);
      pw.y = pkbf(acc[m][nt][2] * inv[m], acc[m][nt][3] * inv[m]);
      int d0 = nt * 16 + l4 * 4;
      *reinterpret_cast<uint2*>(&lds[q * 64 + (d0 ^ sw)]) = pw;
    }
  }
  __syncthreads();
#pragma unroll
  for (int rr2 = 0; rr2 < 2; ++rr2) {
    int q = rr2 * 128 + (tid >> 1), dh = (tid & 1) * 32, sw = (q & 7) << 3;
    size_t orow = ((size_t)(b * SEQ + qt * 256 + q)) * D_MODEL + h * HD + dh;
#pragma unroll
    for (int j = 0; j < 4; ++j) {
      us8 vv = *reinterpret_cast<const us8*>(&lds[q * 64 + ((dh + j * 8) ^ sw)]);
      *reinterpret_cast<us8*>(&aout[orow + j * 8]) = vv;
    }
  }
}

extern "C" void kernel_launch(void* const* d_in, const int* in_sizes, int n_in,
                              void* d_out, int out_size, void* d_ws, size_t ws_size,
                              hipStream_t stream) {
  const float* Q  = (const float*)d_in[0];
  const float* K  = (const float*)d_in[1];
  const float* V  = (const float*)d_in[2];
  const float* Wq = (const float*)d_in[3];
  const float* bq = (const float*)d_in[4];
  const float* Wk = (const float*)d_in[5];
  const float* bk = (const float*)d_in[6];
  const float* Wv = (const float*)d_in[7];
  const float* bv = (const float*)d_in[8];
  const float* Wo = (const float*)d_in[9];
  const float* bo = (const float*)d_in[10];
  float* out = (float*)d_out;

  // workspace (40 MB used)
  unsigned char* ws = (unsigned char*)d_ws;
  const size_t MB = 1024 * 1024;
  unsigned short* wthi = (unsigned short*)(ws);             // 4x W^T hi      (8 MB)
  unsigned short* qh   = (unsigned short*)(ws + 8 * MB);    // q bf16 [B,S,D] (8 MB)
  unsigned short* kh   = (unsigned short*)(ws + 16 * MB);   // k bf16         (8 MB)
  unsigned short* vt   = (unsigned short*)(ws + 24 * MB);   // V^T [B,H,d,S]  (8 MB)
  unsigned short* ah   = (unsigned short*)(ws + 32 * MB);   // attn out bf16  (8 MB)

  prep_weights<<<dim3(4096, 1, 1), 256, 0, stream>>>(Wq, Wk, Wv, Wo, wthi);
  proj_gemm<<<dim3(768, 1, 1), 256, 0, stream>>>(Q, K, V, wthi,
                                                 bq, bk, bv, qh, kh, vt);
  attn_kernel<<<dim3(8, NH, NB), 256, 0, stream>>>(qh, kh, vt, ah);
  out_gemm<<<dim3(512, 1, 1), 256, 0, stream>>>(ah, wthi, bo, out);
}

// Round 16
// 127.584 us; speedup vs baseline: 1.1394x; 1.1394x over previous
//
#include <hip/hip_runtime.h>
#include <cstdint>
#include <cstddef>

#define D_MODEL 1024
#define HD 64
#define NH 16
#define SEQ 2048
#define NB 2

typedef __attribute__((ext_vector_type(8))) short bf8;           // 8 bf16 (4 VGPR)
typedef __attribute__((ext_vector_type(8))) unsigned short us8;
typedef __attribute__((ext_vector_type(4))) unsigned short us4;
typedef __attribute__((ext_vector_type(4))) float f4;

__device__ __forceinline__ float bf2f(unsigned short u) {
  union { unsigned int i; float f; } c; c.i = ((unsigned int)u) << 16; return c.f;
}
__device__ __forceinline__ unsigned short f2bf(float x) {
  union { float f; unsigned int i; } c; c.f = x;
  unsigned int r = (c.i + 0x7FFFu + ((c.i >> 16) & 1u)) >> 16;   // RNE
  return (unsigned short)r;
}
// packed f32x2 -> bf16x2 (RNE), single HW op
__device__ __forceinline__ unsigned int pkbf(float lo, float hi) {
  unsigned int r;
  asm("v_cvt_pk_bf16_f32 %0, %1, %2" : "=v"(r) : "v"(lo), "v"(hi));
  return r;
}
// exp2 via v_exp_f32 (D = 2^S0)
__device__ __forceinline__ float ex2(float x) {
  float r;
  asm("v_exp_f32 %0, %1" : "=v"(r) : "v"(x));
  return r;
}
// 3-input max, single HW op (v_max3_f32)
__device__ __forceinline__ float max3f(float a, float b, float c) {
  float r;
  asm("v_max3_f32 %0, %1, %2, %3" : "=v"(r) : "v"(a), "v"(b), "v"(c));
  return r;
}
__device__ __forceinline__ f4 mfma16(bf8 a, bf8 b, f4 c) {
  return __builtin_amdgcn_mfma_f32_16x16x32_bf16(a, b, c, 0, 0, 0);
}
// async global->LDS, 16B per lane; LDS dest = wave-uniform base + lane*16
__device__ __forceinline__ void gl16(const unsigned short* g, unsigned short* l) {
  __builtin_amdgcn_global_load_lds(
      (const __attribute__((address_space(1))) unsigned int*)g,
      (__attribute__((address_space(3))) unsigned int*)l, 16, 0, 0);
}

#define QSCALE (0.125f * 1.44269504088896f)   // 1/sqrt(64) * log2(e)

// ---------------- prep: weight transpose -> W^T hi (bf16), all 4 mats ----------------
__global__ __launch_bounds__(256) void prep_weights(
    const float* __restrict__ Wq, const float* __restrict__ Wk,
    const float* __restrict__ Wv, const float* __restrict__ Wo,
    unsigned short* __restrict__ wthi) {
  int bid = blockIdx.x;
  int mat = bid >> 10, rem = bid & 1023;
  int kt = (rem >> 5) * 32, nt = (rem & 31) * 32;
  const float* W = (mat == 0) ? Wq : (mat == 1) ? Wk : (mat == 2) ? Wv : Wo;
  unsigned short* oh = wthi + ((size_t)mat << 20);
  __shared__ float ls[32][33];
  int i = threadIdx.x >> 5;
  int jj = threadIdx.x & 31;
#pragma unroll
  for (int ii = 0; ii < 4; ++ii) {
    int r = i + ii * 8;
    ls[r][jj] = W[(size_t)(kt + r) * D_MODEL + nt + jj];
  }
  __syncthreads();
#pragma unroll
  for (int ii = 0; ii < 4; ++ii) {
    int r = i + ii * 8;
    float v = ls[jj][r];
    if (mat == 0) v *= QSCALE;
    oh[(size_t)(nt + r) * D_MODEL + kt + jj] = f2bf(v);
  }
}

// ---------------- proj GEMM: fp32 A with inline bf16 convert, hi-only B ----------------
__global__ __launch_bounds__(256, 3) void proj_gemm(
    const float* __restrict__ Qin, const float* __restrict__ Kin,
    const float* __restrict__ Vin, const unsigned short* __restrict__ wth,
    const float* __restrict__ b0, const float* __restrict__ b1,
    const float* __restrict__ b2,
    unsigned short* __restrict__ qh, unsigned short* __restrict__ kh,
    unsigned short* __restrict__ vt) {
  // 768 = 8 XCDs x 96: wid chunked per XCD; bn fastest within chunk
  int wid = (blockIdx.x & 7) * 96 + (blockIdx.x >> 3);
  int z = wid >> 8, rem = wid & 255, bm = rem >> 3, bn = rem & 7;

  const float* A = (z == 0) ? Qin : (z == 1) ? Kin : Vin;
  const unsigned short* Bh = wth + ((size_t)z << 20);
  const float* bias = (z == 0) ? b0 : (z == 1) ? b1 : b2;
  float bsc = (z == 0) ? QSCALE : 1.0f;

  int tid = threadIdx.x, lane = tid & 63, w = tid >> 6;
  int wr = w >> 1, wc = w & 1, l16 = lane & 15, l4 = lane >> 4;

  __shared__ unsigned short As[2][128 * 32];
  __shared__ unsigned short Bsh[2][128 * 32];

  const float* Ab = A + (size_t)(bm * 128) * D_MODEL;
  const unsigned short* Bhb = Bh + (size_t)(bn * 128) * D_MODEL;

  int r0 = tid >> 2, g0 = tid & 3;
  int r1 = (256 + tid) >> 2, g1 = tid & 3;
  int s0 = (r0 ^ (r0 >> 2)) & 3, s1 = (r1 ^ (r1 >> 2)) & 3;
  size_t so0 = (size_t)r0 * D_MODEL + ((g0 ^ s0) * 8);
  size_t so1 = (size_t)r1 * D_MODEL + ((g1 ^ s1) * 8);
  int ld0 = (w * 64) * 8;
  int ld1 = (256 + w * 64) * 8;

  int rr = tid >> 2, c8 = (tid & 3) * 8;
  int adst[2];
#pragma unroll
  for (int p = 0; p < 2; ++p) {
    int row = p * 64 + rr;
    int sw = (row ^ (row >> 2)) & 3;
    adst[p] = row * 32 + (((tid & 3) ^ sw)) * 8;
  }

  int offA[4], offB[4];
#pragma unroll
  for (int m = 0; m < 4; ++m) {
    int row = wr * 64 + m * 16 + l16;
    int sw = (row ^ (row >> 2)) & 3;
    offA[m] = row * 32 + ((l4 ^ sw)) * 8;
  }
#pragma unroll
  for (int n = 0; n < 4; ++n) {
    int row = wc * 64 + n * 16 + l16;
    int sw = (row ^ (row >> 2)) & 3;
    offB[n] = row * 32 + ((l4 ^ sw)) * 8;
  }

  f4 acc[4][4];
  const f4 zf = {0.f, 0.f, 0.f, 0.f};
#pragma unroll
  for (int m = 0; m < 4; ++m)
#pragma unroll
    for (int n = 0; n < 4; ++n) acc[m][n] = zf;

  {
    float4 x[2][2];
#pragma unroll
    for (int p = 0; p < 2; ++p) {
      const float* src = Ab + (size_t)(p * 64 + rr) * D_MODEL + c8;
      x[p][0] = *reinterpret_cast<const float4*>(src);
      x[p][1] = *reinterpret_cast<const float4*>(src + 4);
    }
    gl16(Bhb + so0, &Bsh[0][ld0]);
    gl16(Bhb + so1, &Bsh[0][ld1]);
#pragma unroll
    for (int p = 0; p < 2; ++p) {
      union { us8 v; unsigned u[4]; } hv;
      hv.u[0] = pkbf(x[p][0].x, x[p][0].y); hv.u[1] = pkbf(x[p][0].z, x[p][0].w);
      hv.u[2] = pkbf(x[p][1].x, x[p][1].y); hv.u[3] = pkbf(x[p][1].z, x[p][1].w);
      *reinterpret_cast<us8*>(&As[0][adst[p]]) = hv.v;
    }
  }
  __syncthreads();

  int cur = 0;
  for (int i = 0; i < 32; ++i) {
    float4 nx[2][2];
    if (i < 31) {
      int ktn = (i + 1) * 32;
#pragma unroll
      for (int p = 0; p < 2; ++p) {
        const float* src = Ab + (size_t)(p * 64 + rr) * D_MODEL + ktn + c8;
        nx[p][0] = *reinterpret_cast<const float4*>(src);
        nx[p][1] = *reinterpret_cast<const float4*>(src + 4);
      }
      gl16(Bhb + ktn + so0, &Bsh[cur ^ 1][ld0]);
      gl16(Bhb + ktn + so1, &Bsh[cur ^ 1][ld1]);
    }
    bf8 a[4], bh[4];
#pragma unroll
    for (int m = 0; m < 4; ++m)
      a[m] = *reinterpret_cast<const bf8*>(&As[cur][offA[m]]);
#pragma unroll
    for (int n = 0; n < 4; ++n)
      bh[n] = *reinterpret_cast<const bf8*>(&Bsh[cur][offB[n]]);
#pragma unroll
    for (int m = 0; m < 4; ++m)
#pragma unroll
      for (int n = 0; n < 4; ++n)
        acc[m][n] = mfma16(a[m], bh[n], acc[m][n]);
    if (i < 31) {
#pragma unroll
      for (int p = 0; p < 2; ++p) {
        union { us8 v; unsigned u[4]; } hv;
        hv.u[0] = pkbf(nx[p][0].x, nx[p][0].y); hv.u[1] = pkbf(nx[p][0].z, nx[p][0].w);
        hv.u[2] = pkbf(nx[p][1].x, nx[p][1].y); hv.u[3] = pkbf(nx[p][1].z, nx[p][1].w);
        *reinterpret_cast<us8*>(&As[cur ^ 1][adst[p]]) = hv.v;
      }
    }
    __syncthreads();
    cur ^= 1;
  }

#pragma unroll
  for (int n = 0; n < 4; ++n) {
    int col = bn * 128 + wc * 64 + n * 16 + l16;
    float bb = bias[col] * bsc;
#pragma unroll
    for (int m = 0; m < 4; ++m) {
      int row0 = bm * 128 + wr * 64 + m * 16 + l4 * 4;
      if (z == 0) {
#pragma unroll
        for (int r = 0; r < 4; ++r)
          qh[(size_t)(row0 + r) * D_MODEL + col] = f2bf(acc[m][n][r] + bb);
      } else if (z == 1) {
#pragma unroll
        for (int r = 0; r < 4; ++r)
          kh[(size_t)(row0 + r) * D_MODEL + col] = f2bf(acc[m][n][r] + bb);
      } else {
        int bb2 = row0 >> 11, ss = row0 & (SEQ - 1);
        int hh2 = col >> 6, dd = col & 63;
        union { us4 s; uint2 u; } pk4;
        pk4.u.x = pkbf(acc[m][n][0] + bb, acc[m][n][1] + bb);
        pk4.u.y = pkbf(acc[m][n][2] + bb, acc[m][n][3] + bb);
        *reinterpret_cast<us4*>(vt + ((size_t)(bb2 * NH + hh2) * HD + dd) * SEQ + ss) = pk4.s;
      }
    }
  }
}

// ---------------- out GEMM (hi-only, fp32 out): 128x64 tile, 512 blocks, XCD swizzle ----------------
__global__ __launch_bounds__(256, 3) void out_gemm(
    const unsigned short* __restrict__ ah, const unsigned short* __restrict__ wth,
    const float* __restrict__ bo, float* __restrict__ o32) {
  int wid = (blockIdx.x & 7) * 64 + (blockIdx.x >> 3);
  int bm = wid >> 4, bn = wid & 15;

  const unsigned short* Bh = wth + ((size_t)3 << 20);
  int tid = threadIdx.x, lane = tid & 63, w = tid >> 6;
  int wr = w >> 1, wc = w & 1, l16 = lane & 15, l4 = lane >> 4;

  __shared__ unsigned short As[2][128 * 32];
  __shared__ unsigned short Bsh[2][64 * 32];

  const unsigned short* Ab = ah + (size_t)(bm * 128) * D_MODEL;
  const unsigned short* Bhb = Bh + (size_t)(bn * 64) * D_MODEL;

  int r0 = tid >> 2, g0 = tid & 3;
  int r1 = (256 + tid) >> 2;
  int s0 = (r0 ^ (r0 >> 2)) & 3, s1 = (r1 ^ (r1 >> 2)) & 3;
  size_t so0 = (size_t)r0 * D_MODEL + ((g0 ^ s0) * 8);
  size_t so1 = (size_t)r1 * D_MODEL + ((g0 ^ s1) * 8);
  int ld0 = (w * 64) * 8;
  int ld1 = (256 + w * 64) * 8;

  int offA[4], offB[2];
#pragma unroll
  for (int m = 0; m < 4; ++m) {
    int row = wr * 64 + m * 16 + l16;
    int sw = (row ^ (row >> 2)) & 3;
    offA[m] = row * 32 + ((l4 ^ sw)) * 8;
  }
#pragma unroll
  for (int n = 0; n < 2; ++n) {
    int row = wc * 32 + n * 16 + l16;
    int sw = (row ^ (row >> 2)) & 3;
    offB[n] = row * 32 + ((l4 ^ sw)) * 8;
  }

  f4 acc[4][2];
  const f4 zf = {0.f, 0.f, 0.f, 0.f};
#pragma unroll
  for (int m = 0; m < 4; ++m)
#pragma unroll
    for (int n = 0; n < 2; ++n) acc[m][n] = zf;

  gl16(Ab + so0, &As[0][ld0]); gl16(Ab + so1, &As[0][ld1]);
  gl16(Bhb + so0, &Bsh[0][ld0]);
  __syncthreads();

  int cur = 0;
  for (int i = 0; i < 32; ++i) {
    if (i < 31) {
      int ktn = (i + 1) * 32;
      gl16(Ab + ktn + so0, &As[cur ^ 1][ld0]); gl16(Ab + ktn + so1, &As[cur ^ 1][ld1]);
      gl16(Bhb + ktn + so0, &Bsh[cur ^ 1][ld0]);
    }
    bf8 a[4], bh[2];
#pragma unroll
    for (int m = 0; m < 4; ++m)
      a[m] = *reinterpret_cast<const bf8*>(&As[cur][offA[m]]);
#pragma unroll
    for (int n = 0; n < 2; ++n)
      bh[n] = *reinterpret_cast<const bf8*>(&Bsh[cur][offB[n]]);
#pragma unroll
    for (int m = 0; m < 4; ++m)
#pragma unroll
      for (int n = 0; n < 2; ++n)
        acc[m][n] = mfma16(a[m], bh[n], acc[m][n]);
    __syncthreads();
    cur ^= 1;
  }

#pragma unroll
  for (int n = 0; n < 2; ++n) {
    int col = bn * 64 + wc * 32 + n * 16 + l16;
    float bb = bo[col];
#pragma unroll
    for (int m = 0; m < 4; ++m) {
      int row0 = bm * 128 + wr * 64 + m * 16 + l4 * 4;
#pragma unroll
      for (int r = 0; r < 4; ++r)
        o32[(size_t)(row0 + r) * D_MODEL + col] = acc[m][n][r] + bb;
    }
  }
}

// ---------------- flash attention: KVBLK=128, paired-window PV (r11 config, reverted) ----------------
// 512 blocks (2/CU, 2 waves/SIMD), 4 waves, 32 q/wave -- the measured optimum of
// the q-per-wave family (16q@4w: 80us r5; 32q@2w: 65us r11; 64q@1w: 81us r15).
__global__ __launch_bounds__(256) void attn_kernel(
    const unsigned short* __restrict__ qh, const unsigned short* __restrict__ kh,
    const unsigned short* __restrict__ vt, unsigned short* __restrict__ aout) {
  // XCD-aware bijective swizzle: 512 blocks, 8 XCDs -> 64 contiguous per XCD
  int orig = blockIdx.x + (blockIdx.y << 4) + (blockIdx.z << 8);
  int swz = ((orig & 7) << 6) + (orig >> 3);
  int qt = swz & 15, h = (swz >> 4) & 15, b = swz >> 8;

  int tid = threadIdx.x;
  int lane = tid & 63, w = tid >> 6;
  int l16 = lane & 15, l4 = lane >> 4;
  int l8r = lane >> 3, l8c = lane & 7;

  __shared__ unsigned short lds[32768];   // [2][8192] K + [2][8192] V^T (64KB)

  const unsigned short* Kh = kh + (size_t)b * SEQ * D_MODEL + h * HD;
  const unsigned short* Vt = vt + (size_t)(b * NH + h) * HD * SEQ;

  // q B-frags: rows qt*128 + w*32 + m*16 + l16
  bf8 qf[2][2];
#pragma unroll
  for (int m = 0; m < 2; ++m) {
    size_t qo = (size_t)(b * SEQ + qt * 128 + w * 32 + m * 16 + l16) * D_MODEL + h * HD + l4 * 8;
    qf[m][0] = *reinterpret_cast<const bf8*>(qh + qo);
    qf[m][1] = *reinterpret_cast<const bf8*>(qh + qo + 32);
  }
  bf8 ones;
#pragma unroll
  for (int j = 0; j < 8; ++j) ones[j] = (short)0x3F80;

  const f4 zf = {0.f, 0.f, 0.f, 0.f};
  f4 acc[2][4];
  f4 accs[2] = {zf, zf};
  float mr[2] = {0.f, 0.f};
#pragma unroll
  for (int m = 0; m < 2; ++m)
#pragma unroll
    for (int nt = 0; nt < 4; ++nt) acc[m][nt] = zf;

  const int sgr = (l8c ^ l8r) * 8;     // K-staging pre-swizzled source granule
  const int swk = l16 & 7;
  const int vsub = ((l4 & 1) << 2);
  const int vrow_in = lane >> 4;       // 0..3 within V staging chunk

  // ---- stage tile 0 (128 keys) into buf 0 ----
  {
#pragma unroll
    for (int j = 0; j < 4; ++j) {
      int s = w * 4 + j;
      gl16(Kh + (size_t)(8 * s + l8r) * D_MODEL + sgr, &lds[0 + s * 512]);
      int row = 4 * s + vrow_in;
      int g = ((lane & 7) ^ (row & 7)) | (lane & 8);
      gl16(Vt + (size_t)row * SEQ + g * 8, &lds[16384 + s * 512]);
    }
  }
  __syncthreads();

  int cur = 0;
  for (int kt = 0; kt < SEQ / 128; ++kt) {
    if (kt < SEQ / 128 - 1) {
      int k0n = (kt + 1) * 128;
      unsigned short* kd = &lds[(cur ^ 1) * 8192];
      unsigned short* vd = &lds[16384 + (cur ^ 1) * 8192];
#pragma unroll
      for (int j = 0; j < 4; ++j) {
        int s = w * 4 + j;
        gl16(Kh + (size_t)(k0n + 8 * s + l8r) * D_MODEL + sgr, kd + s * 512);
        int row = 4 * s + vrow_in;
        int g = ((lane & 7) ^ (row & 7)) | (lane & 8);
        gl16(Vt + (size_t)row * SEQ + k0n + g * 8, vd + s * 512);
      }
    }
    const unsigned short* khb = &lds[cur * 8192];
    const unsigned short* vlb = &lds[16384 + cur * 8192];

#pragma unroll
    for (int h2 = 0; h2 < 2; ++h2) {
      const unsigned short* khh = khb + h2 * 4096;   // rows h2*64.. of [128][64]
      // K A-frags: A[row=key(half-local), k=d]
      bf8 kb[4][2];
#pragma unroll
      for (int c = 0; c < 4; ++c) {
        int row = c * 16 + l16;
        kb[c][0] = *reinterpret_cast<const bf8*>(&khh[row * 64 + ((l4 ^ swk) * 8)]);
        kb[c][1] = *reinterpret_cast<const bf8*>(&khh[row * 64 + (((4 + l4) ^ swk) * 8)]);
      }
      f4 sc[2][4];
      __builtin_amdgcn_s_setprio(1);
#pragma unroll
      for (int m = 0; m < 2; ++m)
#pragma unroll
        for (int c = 0; c < 4; ++c) {
          f4 sv = zf;
          sv = mfma16(kb[c][0], qf[m][0], sv);
          sv = mfma16(kb[c][1], qf[m][1], sv);
          sc[m][c] = sv;
        }
      __builtin_amdgcn_s_setprio(0);
      // V chunks: rows d=nt*16+l16 of [64][128]; granule pos = (gvc^swk) + 8*h2
      uint2 vdr[4][4];
#pragma unroll
      for (int c = 0; c < 4; ++c) {
        int gvc = 2 * c + (l4 >> 1);
        int voff = (((gvc ^ swk) + 8 * h2) << 3) + vsub;
#pragma unroll
        for (int nt = 0; nt < 4; ++nt)
          vdr[c][nt] = *reinterpret_cast<const uint2*>(&vlb[(nt * 16 + l16) * 128 + voff]);
      }
      unsigned Wp[2][4][2];
#pragma unroll
      for (int m = 0; m < 2; ++m) {
        // max over lane's 16 scores via v_max3 (2 ops per quad) then cross-l4
        float tc0 = max3f(sc[m][0][0], sc[m][0][1], fmaxf(sc[m][0][2], sc[m][0][3]));
        float tc1 = max3f(sc[m][1][0], sc[m][1][1], fmaxf(sc[m][1][2], sc[m][1][3]));
        float tc2 = max3f(sc[m][2][0], sc[m][2][1], fmaxf(sc[m][2][2], sc[m][2][3]));
        float tc3 = max3f(sc[m][3][0], sc[m][3][1], fmaxf(sc[m][3][2], sc[m][3][3]));
        float tm = max3f(tc0, tc1, fmaxf(tc2, tc3));
        tm = fmaxf(tm, __shfl_xor(tm, 16));
        tm = fmaxf(tm, __shfl_xor(tm, 32));
        if (__any(tm > mr[m] + 8.0f)) {
          float mn = fmaxf(mr[m], tm);
          float al = ex2(mr[m] - mn);
          mr[m] = mn;
          accs[m][0] *= al; accs[m][1] *= al; accs[m][2] *= al; accs[m][3] *= al;
#pragma unroll
          for (int nt = 0; nt < 4; ++nt) {
            acc[m][nt][0] *= al; acc[m][nt][1] *= al;
            acc[m][nt][2] *= al; acc[m][nt][3] *= al;
          }
        }
#pragma unroll
        for (int c = 0; c < 4; ++c) {
          float p0 = ex2(sc[m][c][0] - mr[m]);
          float p1 = ex2(sc[m][c][1] - mr[m]);
          float p2 = ex2(sc[m][c][2] - mr[m]);
          float p3 = ex2(sc[m][c][3] - mr[m]);
          Wp[m][c][0] = pkbf(p0, p1);
          Wp[m][c][1] = pkbf(p2, p3);
        }
      }
      // PV + denominator: two 16-key windows packed per K=32 MFMA
      __builtin_amdgcn_s_setprio(1);
#pragma unroll
      for (int cp = 0; cp < 2; ++cp) {
        int c0 = cp * 2, c1 = cp * 2 + 1;
#pragma unroll
        for (int m = 0; m < 2; ++m) {
          union { bf8 v; unsigned u[4]; } pu;
          pu.u[0] = Wp[m][c0][0]; pu.u[1] = Wp[m][c0][1];
          pu.u[2] = Wp[m][c1][0]; pu.u[3] = Wp[m][c1][1];
          accs[m] = mfma16(ones, pu.v, accs[m]);
#pragma unroll
          for (int nt = 0; nt < 4; ++nt) {
            union { bf8 v; unsigned u[4]; } vu;
            vu.u[0] = vdr[c0][nt].x; vu.u[1] = vdr[c0][nt].y;
            vu.u[2] = vdr[c1][nt].x; vu.u[3] = vdr[c1][nt].y;
            acc[m][nt] = mfma16(vu.v, pu.v, acc[m][nt]);
          }
        }
      }
      __builtin_amdgcn_s_setprio(0);
    }
    __syncthreads();
    cur ^= 1;
  }

  // epilogue: normalize, transpose O^T -> O via freed LDS
  float inv[2];
#pragma unroll
  for (int m = 0; m < 2; ++m) inv[m] = 1.0f / accs[m][0];
#pragma unroll
  for (int m = 0; m < 2; ++m) {
    int q = w * 32 + m * 16 + l16;
    int sw = (q & 7) << 3;
#pragma unroll
    for (int nt = 0; nt < 4; ++nt) {
      uint2 pw;
      pw.x = pkbf(acc[m][nt][0] * inv[m], acc[m][nt][1] * inv[m]);
      pw.y = pkbf(acc[m][nt][2] * inv[m], acc[m][nt][3] * inv[m]);
      int d0 = nt * 16 + l4 * 4;
      *reinterpret_cast<uint2*>(&lds[q * 64 + (d0 ^ sw)]) = pw;
    }
  }
  __syncthreads();
  {
    int q = tid >> 1, dh = (tid & 1) * 32, sw = (q & 7) << 3;
    size_t orow = ((size_t)(b * SEQ + qt * 128 + q)) * D_MODEL + h * HD + dh;
#pragma unroll
    for (int j = 0; j < 4; ++j) {
      us8 vv = *reinterpret_cast<const us8*>(&lds[q * 64 + ((dh + j * 8) ^ sw)]);
      *reinterpret_cast<us8*>(&aout[orow + j * 8]) = vv;
    }
  }
}

extern "C" void kernel_launch(void* const* d_in, const int* in_sizes, int n_in,
                              void* d_out, int out_size, void* d_ws, size_t ws_size,
                              hipStream_t stream) {
  const float* Q  = (const float*)d_in[0];
  const float* K  = (const float*)d_in[1];
  const float* V  = (const float*)d_in[2];
  const float* Wq = (const float*)d_in[3];
  const float* bq = (const float*)d_in[4];
  const float* Wk = (const float*)d_in[5];
  const float* bk = (const float*)d_in[6];
  const float* Wv = (const float*)d_in[7];
  const float* bv = (const float*)d_in[8];
  const float* Wo = (const float*)d_in[9];
  const float* bo = (const float*)d_in[10];
  float* out = (float*)d_out;

  // workspace (40 MB used)
  unsigned char* ws = (unsigned char*)d_ws;
  const size_t MB = 1024 * 1024;
  unsigned short* wthi = (unsigned short*)(ws);             // 4x W^T hi      (8 MB)
  unsigned short* qh   = (unsigned short*)(ws + 8 * MB);    // q bf16 [B,S,D] (8 MB)
  unsigned short* kh   = (unsigned short*)(ws + 16 * MB);   // k bf16         (8 MB)
  unsigned short* vt   = (unsigned short*)(ws + 24 * MB);   // V^T [B,H,d,S]  (8 MB)
  unsigned short* ah   = (unsigned short*)(ws + 32 * MB);   // attn out bf16  (8 MB)

  prep_weights<<<dim3(4096, 1, 1), 256, 0, stream>>>(Wq, Wk, Wv, Wo, wthi);
  proj_gemm<<<dim3(768, 1, 1), 256, 0, stream>>>(Q, K, V, wthi,
                                                 bq, bk, bv, qh, kh, vt);
  attn_kernel<<<dim3(16, NH, NB), 256, 0, stream>>>(qh, kh, vt, ah);
  out_gemm<<<dim3(512, 1, 1), 256, 0, stream>>>(ah, wthi, bo, out);
}